// Round 1
// baseline (304.517 us; speedup 1.0000x reference)
//
#include <hip/hip_runtime.h>
#include <hip/hip_bf16.h>

#define B_    32
#define CIN_  16
#define COUT_ 16
#define H_    256
#define W_    256

typedef float f32x4 __attribute__((ext_vector_type(4)));
typedef short s16x8 __attribute__((ext_vector_type(8)));

__device__ inline unsigned short f2bf(float f){
  __hip_bfloat16 h = __float2bfloat16(f);
  return __builtin_bit_cast(unsigned short, h);
}

// --- kernel 1: reset running max + pre-pack bf16 weight A-fragments ---
// 5 MFMAs of 16x16x32 cover the K=144 reduction (9 taps x 16 cin), the 5th
// MFMA's upper half (tap 9) gets zero weights. Lane layout: co = lane&15,
// kappa = (lane>>4)*8 + i; tap = 2m + (kappa>>4); ci = kappa&15.
__global__ void setup_kernel(const float* __restrict__ wq,
                             unsigned* __restrict__ wmax,
                             unsigned short* __restrict__ packA){
  int lane = threadIdx.x;           // 0..63
  if (lane == 0) *wmax = 0u;
  int co = lane & 15;
  int g  = lane >> 4;
  for (int m = 0; m < 5; ++m){
    for (int i = 0; i < 8; ++i){
      int kappa = g*8 + i;
      int tap = 2*m + (kappa >> 4);
      int ci  = kappa & 15;
      float v = (tap <= 8) ? wq[(co*16 + ci)*9 + tap] : 0.f;
      packA[(m*64 + lane)*8 + i] = f2bf(v);
    }
  }
}

// --- kernel 2: global max|x| ---
__global__ __launch_bounds__(256) void absmax_kernel(const float* __restrict__ x,
                                                     unsigned* __restrict__ wmax,
                                                     int n4){
  int idx = blockIdx.x*blockDim.x + threadIdx.x;
  int stride = gridDim.x*blockDim.x;
  float m = 0.f;
  for (int i = idx; i < n4; i += stride){
    float4 v = reinterpret_cast<const float4*>(x)[i];
    m = fmaxf(m, fmaxf(fmaxf(fabsf(v.x), fabsf(v.y)), fmaxf(fabsf(v.z), fabsf(v.w))));
  }
  #pragma unroll
  for (int off = 32; off > 0; off >>= 1)
    m = fmaxf(m, __shfl_xor(m, off));
  if ((threadIdx.x & 63) == 0) atomicMax(wmax, __float_as_uint(m));
}

// --- kernel 3: quantize + int conv (exact in bf16 MFMA) + dequant + bias ---
// block = (b, h, 64-wide w strip); 4 waves, each one 16(cout)x16(w) MFMA tile.
// LDS layout [row(3)][col(66)][ci(16)] bf16 so B-fragments are ds_read_b128.
__global__ __launch_bounds__(256) void conv_kernel(const float* __restrict__ x,
                                                   const float* __restrict__ sw,
                                                   const float* __restrict__ bias,
                                                   const unsigned* __restrict__ wmax,
                                                   const unsigned short* __restrict__ packA,
                                                   float* __restrict__ out){
  const float s = __uint_as_float(*wmax) * 0.0078125f;  // max|x| / 128
  const int tid = threadIdx.x;
  const int bx  = blockIdx.x;
  const int wt = bx & 3;
  const int h  = (bx >> 2) & 255;
  const int b  = bx >> 10;
  const int w0 = wt * 64;

  __shared__ __align__(16) unsigned short lds[3*66*16];

  const int lane = tid & 63;
  const int grp  = tid >> 6;   // wave id 0..3

  // staging: 48 (row,ci) pairs, each 66 cols; quantize on the fly
  for (int p = grp; p < 48; p += 4){
    int r  = p >> 4;
    int ci = p & 15;
    int hin = h + r - 1;
    const bool rowok = (unsigned)hin < 256u;
    const float* xrow = x + ((((b*16 + ci) << 8) + (rowok ? hin : 0)) << 8);
    {
      int c = lane;
      int win = w0 - 1 + c;
      float xv = (rowok && (unsigned)win < 256u) ? xrow[win] : 0.f;
      float q = rintf(fminf(fmaxf(xv / s, -127.f), 127.f));
      lds[(r*66 + c)*16 + ci] = f2bf(q);
    }
    if (lane < 2){
      int c = 64 + lane;
      int win = w0 - 1 + c;
      float xv = (rowok && (unsigned)win < 256u) ? xrow[win] : 0.f;
      float q = rintf(fminf(fmaxf(xv / s, -127.f), 127.f));
      lds[(r*66 + c)*16 + ci] = f2bf(q);
    }
  }
  __syncthreads();

  const int colg = lane & 15;
  const int g    = lane >> 4;
  const int ci0  = (g & 1) * 8;   // which 8-ci block this lane group reads
  const int tlg  = g >> 1;        // tap_local: groups 0,1 -> tap 2m; 2,3 -> 2m+1

  f32x4 acc = {0.f, 0.f, 0.f, 0.f};
  const s16x8* pA = reinterpret_cast<const s16x8*>(packA);
  #pragma unroll
  for (int m = 0; m < 5; ++m){
    int tap = 2*m + tlg;
    if (tap > 8) tap = 8;         // tap 9: A is zero, B value irrelevant (finite)
    int r  = (tap*11) >> 5;       // tap/3 for tap in [0,8]
    int kw = tap - r*3;
    int c  = grp*16 + colg + kw;  // includes the -1 halo shift
    s16x8 bv = *reinterpret_cast<const s16x8*>(&lds[(r*66 + c)*16 + ci0]);
    s16x8 av = pA[m*64 + lane];
    acc = __builtin_amdgcn_mfma_f32_16x16x32_bf16(av, bv, acc, 0, 0, 0);
  }

  // D layout: col = lane&15 (pixel), row = (lane>>4)*4 + j (cout)
  const int w = w0 + grp*16 + colg;
  #pragma unroll
  for (int j = 0; j < 4; ++j){
    int co = g*4 + j;
    float o = acc[j] * (s * sw[co]) + bias[co];
    out[((((b*16 + co) << 8) + h) << 8) + w] = o;
  }
}

extern "C" void kernel_launch(void* const* d_in, const int* in_sizes, int n_in,
                              void* d_out, int out_size, void* d_ws, size_t ws_size,
                              hipStream_t stream){
  const float* x    = (const float*)d_in[0];
  const float* wq   = (const float*)d_in[1];
  const float* sw   = (const float*)d_in[2];
  const float* bias = (const float*)d_in[3];
  float* out = (float*)d_out;
  unsigned* wmax = (unsigned*)d_ws;
  unsigned short* packA = (unsigned short*)((char*)d_ws + 64);

  setup_kernel<<<1, 64, 0, stream>>>(wq, wmax, packA);
  absmax_kernel<<<2048, 256, 0, stream>>>(x, wmax, (B_*CIN_*H_*W_)/4);
  conv_kernel<<<B_*H_*(W_/64), 256, 0, stream>>>(x, sw, bias, wmax, packA, out);
}

// Round 3
// 148.500 us; speedup vs baseline: 2.0506x; 2.0506x over previous
//
#include <hip/hip_runtime.h>
#include <hip/hip_bf16.h>

#define B_    32
#define CIN_  16
#define COUT_ 16
#define H_    256
#define W_    256
#define HP    258
#define WP    260
// ws layout: [0,4)=wmax | [64,5184)=packA (5120 B) | [8192, ...)=xq
// xq: [b][HP][WP][16] ushort (bf16), halo rows/cols zeroed

typedef float f32x4 __attribute__((ext_vector_type(4)));
typedef short s16x8 __attribute__((ext_vector_type(8)));
typedef unsigned short u16x4 __attribute__((ext_vector_type(4)));

__device__ inline unsigned short f2bf(float f){
  __hip_bfloat16 h = __float2bfloat16(f);
  return __builtin_bit_cast(unsigned short, h);
}

// --- kernel 1: reset running max + pre-pack bf16 weight A-fragments ---
// 5 MFMAs of 16x16x32 cover K=144 (9 taps x 16 cin); 5th MFMA upper half
// (tap 9) gets zero weights. A lane layout: co = lane&15, kappa = (lane>>4)*8+i;
// tap = 2m + (kappa>>4), ci = kappa&15.
__global__ void setup_kernel(const float* __restrict__ wq,
                             unsigned* __restrict__ wmax,
                             unsigned short* __restrict__ packA){
  int lane = threadIdx.x;           // 0..63
  if (lane == 0) *wmax = 0u;
  int co = lane & 15;
  int g  = lane >> 4;
  for (int m = 0; m < 5; ++m){
    for (int i = 0; i < 8; ++i){
      int kappa = g*8 + i;
      int tap = 2*m + (kappa >> 4);
      int ci  = kappa & 15;
      float v = (tap <= 8) ? wq[(co*16 + ci)*9 + tap] : 0.f;
      packA[(m*64 + lane)*8 + i] = f2bf(v);
    }
  }
}

// --- kernel 2: global max|x|, one atomic per BLOCK ---
__global__ __launch_bounds__(256) void absmax_kernel(const float* __restrict__ x,
                                                     unsigned* __restrict__ wmax,
                                                     int n4){
  __shared__ float red[4];
  int idx = blockIdx.x*blockDim.x + threadIdx.x;
  int stride = gridDim.x*blockDim.x;
  float m = 0.f;
  for (int i = idx; i < n4; i += stride){
    float4 v = reinterpret_cast<const float4*>(x)[i];
    m = fmaxf(m, fmaxf(fmaxf(fabsf(v.x), fabsf(v.y)), fmaxf(fabsf(v.z), fabsf(v.w))));
  }
  #pragma unroll
  for (int off = 32; off > 0; off >>= 1)
    m = fmaxf(m, __shfl_xor(m, off));
  int lane = threadIdx.x & 63, wid = threadIdx.x >> 6;
  if (lane == 0) red[wid] = m;
  __syncthreads();
  if (threadIdx.x == 0){
    float mm = fmaxf(fmaxf(red[0], red[1]), fmaxf(red[2], red[3]));
    atomicMax(wmax, __float_as_uint(mm));
  }
}

// --- kernel 3: quantize + transpose to padded channel-last bf16 ---
// block = (b, h). Phase 1: coalesced float4 reads, quantize, LDS [ci][WP].
// Phase 2: per-pixel 16-ci gather, 32B global writes.
__global__ __launch_bounds__(256) void quant_kernel(const float* __restrict__ x,
                                                    const unsigned* __restrict__ wmax,
                                                    unsigned short* __restrict__ xq){
  const float s = __uint_as_float(*wmax) * 0.0078125f;  // max|x| / 128
  const int b = blockIdx.x >> 8;
  const int h = blockIdx.x & 255;
  const int t = threadIdx.x;
  __shared__ __align__(8) unsigned short lds[16*WP];

  #pragma unroll
  for (int i = 0; i < 4; ++i){
    int lin = t + i*256;          // 0..1023
    int ci  = lin >> 6;
    int w4  = lin & 63;
    float4 v = reinterpret_cast<const float4*>(x + ((((b*16 + ci) << 8) + h) << 8))[w4];
    u16x4 q;
    q[0] = f2bf(rintf(fminf(fmaxf(v.x / s, -127.f), 127.f)));
    q[1] = f2bf(rintf(fminf(fmaxf(v.y / s, -127.f), 127.f)));
    q[2] = f2bf(rintf(fminf(fmaxf(v.z / s, -127.f), 127.f)));
    q[3] = f2bf(rintf(fminf(fmaxf(v.w / s, -127.f), 127.f)));
    *reinterpret_cast<u16x4*>(&lds[ci*WP + w4*4]) = q;
  }
  __syncthreads();

  // main row: pixel p = t, padded coords (h+1, p+1)
  s16x8 lo, hi;
  #pragma unroll
  for (int ci = 0; ci < 8; ++ci) lo[ci] = (short)lds[ci*WP + t];
  #pragma unroll
  for (int ci = 0; ci < 8; ++ci) hi[ci] = (short)lds[(ci + 8)*WP + t];
  s16x8* dst = reinterpret_cast<s16x8*>(xq + ((b*HP + h + 1)*WP + (t + 1))*16);
  dst[0] = lo; dst[1] = hi;

  // col halo for this row: pixels wp=0 and wp=257 (2 x 32B)
  if (t < 4){
    int p = (t >> 1) ? 257 : 0;
    f32x4 z = {0.f, 0.f, 0.f, 0.f};
    reinterpret_cast<f32x4*>(xq + ((b*HP + h + 1)*WP + p)*16)[t & 1] = z;
  }
  // row halos: h==0 zeroes hp=0, h==255 zeroes hp=257 (520 x 16B each)
  if (h == 0 || h == 255){
    int hp = (h == 0) ? 0 : 257;
    f32x4 z = {0.f, 0.f, 0.f, 0.f};
    f32x4* row = reinterpret_cast<f32x4*>(xq + (b*HP + hp)*WP*16);
    for (int c = t; c < 520; c += 256) row[c] = z;
  }
}

// --- kernel 4: conv via direct 16B global B-fragment loads (no LDS) ---
__global__ __launch_bounds__(256) void conv_kernel(const unsigned short* __restrict__ xq,
                                                   const float* __restrict__ sw,
                                                   const float* __restrict__ bias,
                                                   const unsigned* __restrict__ wmax,
                                                   const unsigned short* __restrict__ packA,
                                                   float* __restrict__ out){
  const float s = __uint_as_float(*wmax) * 0.0078125f;
  const int bx  = blockIdx.x;
  const int wt = bx & 3;
  const int h  = (bx >> 2) & 255;
  const int b  = bx >> 10;

  const int tid  = threadIdx.x;
  const int lane = tid & 63;
  const int grp  = tid >> 6;          // wave 0..3
  const int colg = lane & 15;
  const int g    = lane >> 4;
  const int ci0  = (g & 1) * 8;
  const int tlg  = g >> 1;            // 0: even taps, 1: odd taps

  const int pix = wt*64 + grp*16 + colg;           // 0..255
  const unsigned short* base = xq + ((b*HP + h)*WP + pix)*16 + ci0;
  const s16x8* pA = reinterpret_cast<const s16x8*>(packA);

  f32x4 acc = {0.f, 0.f, 0.f, 0.f};
  #pragma unroll
  for (int m = 0; m < 5; ++m){
    const int tapA = 2*m;
    const int tapB = (2*m + 1 > 8) ? 8 : 2*m + 1;   // tap 9: A=0, read tap 8
    const int offA = ((tapA/3)*WP + tapA%3)*16;
    const int offB = ((tapB/3)*WP + tapB%3)*16;
    int off = tlg ? offB : offA;
    s16x8 bv = *reinterpret_cast<const s16x8*>(base + off);
    acc = __builtin_amdgcn_mfma_f32_16x16x32_bf16(pA[m*64 + lane], bv, acc, 0, 0, 0);
  }

  // D layout: col = lane&15 (pixel), row = (lane>>4)*4 + j (cout)
  const int w = pix;
  #pragma unroll
  for (int j = 0; j < 4; ++j){
    int co = g*4 + j;
    float o = acc[j] * (s * sw[co]) + bias[co];
    out[((((b*16 + co) << 8) + h) << 8) + w] = o;
  }
}

// --- fallback (round-1 fused conv) if workspace too small for xq ---
__global__ __launch_bounds__(256) void conv_fallback(const float* __restrict__ x,
                                                     const float* __restrict__ sw,
                                                     const float* __restrict__ bias,
                                                     const unsigned* __restrict__ wmax,
                                                     const unsigned short* __restrict__ packA,
                                                     float* __restrict__ out){
  const float s = __uint_as_float(*wmax) * 0.0078125f;
  const int tid = threadIdx.x;
  const int bx  = blockIdx.x;
  const int wt = bx & 3;
  const int h  = (bx >> 2) & 255;
  const int b  = bx >> 10;
  const int w0 = wt * 64;
  __shared__ __align__(16) unsigned short lds[3*66*16];
  const int lane = tid & 63;
  const int grp  = tid >> 6;
  for (int p = grp; p < 48; p += 4){
    int r  = p >> 4;
    int ci = p & 15;
    int hin = h + r - 1;
    const bool rowok = (unsigned)hin < 256u;
    const float* xrow = x + ((((b*16 + ci) << 8) + (rowok ? hin : 0)) << 8);
    {
      int c = lane;
      int win = w0 - 1 + c;
      float xv = (rowok && (unsigned)win < 256u) ? xrow[win] : 0.f;
      lds[(r*66 + c)*16 + ci] = f2bf(rintf(fminf(fmaxf(xv / s, -127.f), 127.f)));
    }
    if (lane < 2){
      int c = 64 + lane;
      int win = w0 - 1 + c;
      float xv = (rowok && (unsigned)win < 256u) ? xrow[win] : 0.f;
      lds[(r*66 + c)*16 + ci] = f2bf(rintf(fminf(fmaxf(xv / s, -127.f), 127.f)));
    }
  }
  __syncthreads();
  const int colg = lane & 15;
  const int g    = lane >> 4;
  const int ci0  = (g & 1) * 8;
  const int tlg  = g >> 1;
  f32x4 acc = {0.f, 0.f, 0.f, 0.f};
  const s16x8* pA = reinterpret_cast<const s16x8*>(packA);
  #pragma unroll
  for (int m = 0; m < 5; ++m){
    int tap = 2*m + tlg;
    if (tap > 8) tap = 8;
    int r  = (tap*11) >> 5;
    int kw = tap - r*3;
    int c  = grp*16 + colg + kw;
    s16x8 bv = *reinterpret_cast<const s16x8*>(&lds[(r*66 + c)*16 + ci0]);
    acc = __builtin_amdgcn_mfma_f32_16x16x32_bf16(pA[m*64 + lane], bv, acc, 0, 0, 0);
  }
  const int w = w0 + grp*16 + colg;
  #pragma unroll
  for (int j = 0; j < 4; ++j){
    int co = g*4 + j;
    float o = acc[j] * (s * sw[co]) + bias[co];
    out[((((b*16 + co) << 8) + h) << 8) + w] = o;
  }
}

extern "C" void kernel_launch(void* const* d_in, const int* in_sizes, int n_in,
                              void* d_out, int out_size, void* d_ws, size_t ws_size,
                              hipStream_t stream){
  const float* x    = (const float*)d_in[0];
  const float* wq   = (const float*)d_in[1];
  const float* sw   = (const float*)d_in[2];
  const float* bias = (const float*)d_in[3];
  float* out = (float*)d_out;
  unsigned* wmax = (unsigned*)d_ws;
  unsigned short* packA = (unsigned short*)((char*)d_ws + 64);   // [64, 5184)
  unsigned short* xq = (unsigned short*)((char*)d_ws + 8192);    // AFTER packA!

  const size_t need = 8192 + (size_t)B_*HP*WP*16*2;  // ~68.7 MB

  setup_kernel<<<1, 64, 0, stream>>>(wq, wmax, packA);
  absmax_kernel<<<2048, 256, 0, stream>>>(x, wmax, (B_*CIN_*H_*W_)/4);
  if (ws_size >= need){
    quant_kernel<<<B_*H_, 256, 0, stream>>>(x, wmax, xq);
    conv_kernel<<<B_*H_*(W_/64), 256, 0, stream>>>(xq, sw, bias, wmax, packA, out);
  } else {
    conv_fallback<<<B_*H_*(W_/64), 256, 0, stream>>>(x, sw, bias, wmax, packA, out);
  }
}

// Round 4
// 123.571 us; speedup vs baseline: 2.4643x; 1.2017x over previous
//
#include <hip/hip_runtime.h>
#include <hip/hip_bf16.h>

#define B_    32
#define H_    256
#define W_    256
#define ROWS  8            // output rows per block
#define LR    (ROWS + 2)   // 10 LDS rows (halo)
#define LC    66           // live cols (64 strip + 2 halo)
#define LCP   68           // padded cols -> row stride 136 16B-units (mult of 8, keeps XOR bijective)
// ws layout: [0,4)=wmax | [64,5184)=packA (5120 B)

typedef float f32x4 __attribute__((ext_vector_type(4)));
typedef short s16x8 __attribute__((ext_vector_type(8)));

__device__ inline unsigned short f2bf(float f){
  __hip_bfloat16 h = __float2bfloat16(f);
  return __builtin_bit_cast(unsigned short, h);
}

// --- kernel 1: reset running max + pre-pack bf16 weight A-fragments ---
// 5 MFMAs of 16x16x32 cover K=144 (9 taps x 16 cin); 5th MFMA upper half
// (tap 9) is zero weights. A lane layout: co = lane&15, kappa = (lane>>4)*8+i;
// tap = 2m + (kappa>>4), ci = kappa&15.   (verified passing in rounds 1,3)
__global__ void setup_kernel(const float* __restrict__ wq,
                             unsigned* __restrict__ wmax,
                             unsigned short* __restrict__ packA){
  int lane = threadIdx.x;           // 0..63
  if (lane == 0) *wmax = 0u;
  int co = lane & 15;
  int g  = lane >> 4;
  for (int m = 0; m < 5; ++m){
    for (int i = 0; i < 8; ++i){
      int kappa = g*8 + i;
      int tap = 2*m + (kappa >> 4);
      int ci  = kappa & 15;
      float v = (tap <= 8) ? wq[(co*16 + ci)*9 + tap] : 0.f;
      packA[(m*64 + lane)*8 + i] = f2bf(v);
    }
  }
}

// --- kernel 2: global max|x|, one atomic per block ---
__global__ __launch_bounds__(256) void absmax_kernel(const float* __restrict__ x,
                                                     unsigned* __restrict__ wmax,
                                                     int n4){
  __shared__ float red[4];
  int idx = blockIdx.x*blockDim.x + threadIdx.x;
  int stride = gridDim.x*blockDim.x;
  float m = 0.f;
  for (int i = idx; i < n4; i += stride){
    float4 v = reinterpret_cast<const float4*>(x)[i];
    m = fmaxf(m, fmaxf(fmaxf(fabsf(v.x), fabsf(v.y)), fmaxf(fabsf(v.z), fabsf(v.w))));
  }
  #pragma unroll
  for (int off = 32; off > 0; off >>= 1)
    m = fmaxf(m, __shfl_xor(m, off));
  int lane = threadIdx.x & 63, wid = threadIdx.x >> 6;
  if (lane == 0) red[wid] = m;
  __syncthreads();
  if (threadIdx.x == 0){
    float mm = fmaxf(fmaxf(red[0], red[1]), fmaxf(red[2], red[3]));
    atomicMax(wmax, __float_as_uint(mm));
  }
}

// --- kernel 3: fused quantize + int conv (exact in bf16 MFMA) + dequant ---
// block = (b, 8-row group, 64-px strip). Phase Q: quantize the 10x66x16 halo
// tile of x into XOR-swizzled LDS. Phase C: 4 waves x (2 rows x 4 chunks x
// 5 MFMAs) = 40 MFMAs/wave from LDS.
__global__ __launch_bounds__(256) void fconv_kernel(const float* __restrict__ x,
                                                    const float* __restrict__ sw,
                                                    const float* __restrict__ bias,
                                                    const unsigned* __restrict__ wmax,
                                                    const unsigned short* __restrict__ packA,
                                                    float* __restrict__ out){
  const float s = __uint_as_float(*wmax) * 0.0078125f;  // max|x| / 128
  const int bx    = blockIdx.x;
  const int strip = bx & 3;
  const int hg    = (bx >> 2) & 31;
  const int b     = bx >> 7;
  const int w0    = strip * 64;
  const int h0    = hg * ROWS;

  __shared__ __align__(16) unsigned short lds[LR*LCP*16];
  s16x8* ldsv = reinterpret_cast<s16x8*>(lds);

  const int tid  = threadIdx.x;
  const int lane = tid & 63;
  const int wid  = tid >> 6;

  // ---- phase Q: quantize into swizzled LDS ----
  // group gi = (r, ci-half); lanes cover cols 0..63; cols 64,65 in tail step.
  for (int gi = wid; gi < LR*2; gi += 4){
    int r = gi >> 1, half = gi & 1;
    int hin = h0 + r - 1;
    bool rowok = (unsigned)hin < 256u;
    const float* xp = x + ((size_t)(b*16 + half*8) << 16) + (size_t)(rowok ? hin : 0)*256;
    int c = lane;
    int win = w0 - 1 + c;
    bool ok = rowok && ((unsigned)win < 256u);
    s16x8 qv;
    #pragma unroll
    for (int ci = 0; ci < 8; ++ci){
      float v = ok ? xp[((size_t)ci << 16) + win] : 0.f;
      qv[ci] = (short)f2bf(rintf(fminf(fmaxf(v / s, -127.f), 127.f)));
    }
    int u = (r*(LCP*2) + c*2 + half) ^ ((c >> 2) & 7);
    ldsv[u] = qv;
  }
  // tail: cols 64,65 for all (r, half): 40 16B-units, one per thread
  if (tid < LR*4){
    int c    = 64 + (tid & 1);
    int half = (tid >> 1) & 1;
    int r    = tid >> 2;
    int hin = h0 + r - 1;
    bool rowok = (unsigned)hin < 256u;
    int win = w0 - 1 + c;
    bool ok = rowok && ((unsigned)win < 256u);
    const float* xp = x + ((size_t)(b*16 + half*8) << 16) + (size_t)(rowok ? hin : 0)*256;
    s16x8 qv;
    #pragma unroll
    for (int ci = 0; ci < 8; ++ci){
      float v = ok ? xp[((size_t)ci << 16) + win] : 0.f;
      qv[ci] = (short)f2bf(rintf(fminf(fmaxf(v / s, -127.f), 127.f)));
    }
    int u = (r*(LCP*2) + c*2 + half) ^ ((c >> 2) & 7);
    ldsv[u] = qv;
  }
  __syncthreads();

  // ---- phase C: MFMA conv from LDS ----
  const int colg = lane & 15;
  const int g    = lane >> 4;
  const int hlf  = g & 1;        // ci half this lane reads
  const int tlg  = g >> 1;       // 0: even taps, 1: odd taps

  int kr[5], kw[5];
  #pragma unroll
  for (int m = 0; m < 5; ++m){
    int t = 2*m + tlg; if (t > 8) t = 8;   // tap 9: A=0, read tap 8 (finite)
    kr[m] = (t*11) >> 5;                   // t/3 for t in [0,8]
    kw[m] = t - kr[m]*3;
  }
  s16x8 A[5];
  const s16x8* pA = reinterpret_cast<const s16x8*>(packA);
  #pragma unroll
  for (int m = 0; m < 5; ++m) A[m] = pA[m*64 + lane];

  f32x4 acc[2][4] = {};
  #pragma unroll
  for (int q = 0; q < 2; ++q){
    const int r_out = wid*2 + q;
    #pragma unroll
    for (int n = 0; n < 4; ++n){
      #pragma unroll
      for (int m = 0; m < 5; ++m){
        int c = n*16 + colg + kw[m];
        int u = ((r_out + kr[m])*(LCP*2) + c*2 + hlf) ^ ((c >> 2) & 7);
        s16x8 bv = ldsv[u];
        acc[q][n] = __builtin_amdgcn_mfma_f32_16x16x32_bf16(A[m], bv, acc[q][n], 0, 0, 0);
      }
    }
  }

  // ---- epilogue: dequant + bias; D layout col=lane&15 (pixel), row=g*4+j (cout)
  #pragma unroll
  for (int j = 0; j < 4; ++j){
    const int co = g*4 + j;
    const float sc = s * sw[co];
    const float bb = bias[co];
    #pragma unroll
    for (int q = 0; q < 2; ++q){
      const int h = h0 + wid*2 + q;
      float* op = out + ((size_t)(b*16 + co) << 16) + h*256 + w0 + colg;
      #pragma unroll
      for (int n = 0; n < 4; ++n)
        op[n*16] = acc[q][n][j] * sc + bb;
    }
  }
}

extern "C" void kernel_launch(void* const* d_in, const int* in_sizes, int n_in,
                              void* d_out, int out_size, void* d_ws, size_t ws_size,
                              hipStream_t stream){
  const float* x    = (const float*)d_in[0];
  const float* wq   = (const float*)d_in[1];
  const float* sw   = (const float*)d_in[2];
  const float* bias = (const float*)d_in[3];
  float* out = (float*)d_out;
  unsigned* wmax = (unsigned*)d_ws;
  unsigned short* packA = (unsigned short*)((char*)d_ws + 64);

  setup_kernel<<<1, 64, 0, stream>>>(wq, wmax, packA);
  absmax_kernel<<<2048, 256, 0, stream>>>(x, wmax, (B_*16*H_*W_)/4);
  fconv_kernel<<<B_*(H_/ROWS)*(W_/64), 256, 0, stream>>>(x, sw, bias, wmax, packA, out);
}

// Round 5
// 117.609 us; speedup vs baseline: 2.5892x; 1.0507x over previous
//
#include <hip/hip_runtime.h>
#include <hip/hip_bf16.h>

#define B_    32
#define H_    256
#define W_    256
#define ROWS  8            // output rows per block
#define LR    (ROWS + 2)   // 10 LDS rows (halo)
#define LCP   68           // padded cols -> row stride 136 16B-units (mult of 8 keeps XOR bijective)
// ws layout: [0,4)=wmax | [64,5184)=packA (5120 B)

typedef float f32x4 __attribute__((ext_vector_type(4)));
typedef short s16x8 __attribute__((ext_vector_type(8)));

__device__ inline unsigned short f2bf(float f){
  __hip_bfloat16 h = __float2bfloat16(f);
  return __builtin_bit_cast(unsigned short, h);
}

// exact round-half-even of x/s via reciprocal + exact fma residual correction
__device__ inline float quant1(float v, float rinv, float s, float hs){
  float q0 = rintf(v * rinv);
  float d  = fmaf(q0, -s, v);        // ~ s*(v/s - q0), one rounding
  q0 += (d >  hs) ? 1.f : 0.f;
  q0 -= (d < -hs) ? 1.f : 0.f;
  return fminf(fmaxf(q0, -127.f), 127.f);
}

// --- kernel 1: reset running max + pre-pack bf16 weight A-fragments ---
// 5 MFMAs of 16x16x32 cover K=144 (9 taps x 16 cin); 5th MFMA upper half
// (tap 9) is zero weights. A lane layout: co = lane&15, kappa = (lane>>4)*8+i;
// tap = 2m + (kappa>>4), ci = kappa&15.   (verified rounds 1,3,4)
__global__ void setup_kernel(const float* __restrict__ wq,
                             unsigned* __restrict__ wmax,
                             unsigned short* __restrict__ packA){
  int lane = threadIdx.x;           // 0..63
  if (lane == 0) *wmax = 0u;
  int co = lane & 15;
  int g  = lane >> 4;
  for (int m = 0; m < 5; ++m){
    for (int i = 0; i < 8; ++i){
      int kappa = g*8 + i;
      int tap = 2*m + (kappa >> 4);
      int ci  = kappa & 15;
      float v = (tap <= 8) ? wq[(co*16 + ci)*9 + tap] : 0.f;
      packA[(m*64 + lane)*8 + i] = f2bf(v);
    }
  }
}

// --- kernel 2: global max|x|, one atomic per block ---
__global__ __launch_bounds__(256) void absmax_kernel(const float* __restrict__ x,
                                                     unsigned* __restrict__ wmax,
                                                     int n4){
  __shared__ float red[4];
  int idx = blockIdx.x*blockDim.x + threadIdx.x;
  int stride = gridDim.x*blockDim.x;
  float m = 0.f;
  for (int i = idx; i < n4; i += stride){
    float4 v = reinterpret_cast<const float4*>(x)[i];
    m = fmaxf(m, fmaxf(fmaxf(fabsf(v.x), fabsf(v.y)), fmaxf(fabsf(v.z), fabsf(v.w))));
  }
  #pragma unroll
  for (int off = 32; off > 0; off >>= 1)
    m = fmaxf(m, __shfl_xor(m, off));
  int lane = threadIdx.x & 63, wid = threadIdx.x >> 6;
  if (lane == 0) red[wid] = m;
  __syncthreads();
  if (threadIdx.x == 0){
    float mm = fmaxf(fmaxf(red[0], red[1]), fmaxf(red[2], red[3]));
    atomicMax(wmax, __float_as_uint(mm));
  }
}

// --- kernel 3: fused quantize + int conv (exact in bf16 MFMA) + dequant ---
__global__ __launch_bounds__(256) void fconv_kernel(const float* __restrict__ x,
                                                    const float* __restrict__ sw,
                                                    const float* __restrict__ bias,
                                                    const unsigned* __restrict__ wmax,
                                                    const unsigned short* __restrict__ packA,
                                                    float* __restrict__ out){
  const float s    = __uint_as_float(*wmax) * 0.0078125f;  // max|x| / 128
  const float rinv = 1.0f / s;
  const float hs   = 0.5f * s;
  const int bx    = blockIdx.x;
  const int strip = bx & 3;
  const int hg    = (bx >> 2) & 31;
  const int b     = bx >> 7;
  const int w0    = strip * 64;
  const int h0    = hg * ROWS;

  __shared__ __align__(16) unsigned short lds[LR*LCP*16];
  s16x8* ldsv = reinterpret_cast<s16x8*>(lds);

  const int tid  = threadIdx.x;
  const int lane = tid & 63;
  const int wid  = tid >> 6;

  // ---- phase Q: quantize the 10x66x16 halo tile into swizzled LDS ----
  // group k -> gi = wid + 4k; r = gi>>1, half = gi&1; lane covers cols 0..63.
  const int c   = lane;
  const int win = w0 - 1 + c;
  const bool colok = (unsigned)win < 256u;

  int   grp_r[5], grp_half[5];
  const float* grp_p[5];
  bool  grp_ok[5];
  #pragma unroll
  for (int k = 0; k < 5; ++k){
    int gi = wid + 4*k;
    int r = gi >> 1, half = gi & 1;
    int hin = h0 + r - 1;
    bool rowok = (unsigned)hin < 256u;
    grp_r[k] = r; grp_half[k] = half;
    grp_ok[k] = rowok && colok;
    grp_p[k] = x + ((size_t)(b*16 + half*8) << 16) + (size_t)(rowok ? hin : 0)*256 + win;
  }

  float v[5][8];
  // batch A: groups 0..2 (24 loads in flight)
  #pragma unroll
  for (int k = 0; k < 3; ++k)
    #pragma unroll
    for (int ci = 0; ci < 8; ++ci)
      v[k][ci] = grp_ok[k] ? grp_p[k][(size_t)ci << 16] : 0.f;
  // tail loads: cols 64,65 (40 threads, 8 loads each)
  float tv[8];
  int t_r = 0, t_half = 0, t_c = 0;
  bool t_act = tid < LR*4;
  if (t_act){
    t_c    = 64 + (tid & 1);
    t_half = (tid >> 1) & 1;
    t_r    = tid >> 2;
    int hin = h0 + t_r - 1;
    bool rowok = (unsigned)hin < 256u;
    int twin = w0 - 1 + t_c;
    bool ok = rowok && ((unsigned)twin < 256u);
    const float* xp = x + ((size_t)(b*16 + t_half*8) << 16) + (size_t)(rowok ? hin : 0)*256 + twin;
    #pragma unroll
    for (int ci = 0; ci < 8; ++ci)
      tv[ci] = ok ? xp[(size_t)ci << 16] : 0.f;
  }
  // batch B: groups 3..4 (16 loads in flight)
  #pragma unroll
  for (int k = 3; k < 5; ++k)
    #pragma unroll
    for (int ci = 0; ci < 8; ++ci)
      v[k][ci] = grp_ok[k] ? grp_p[k][(size_t)ci << 16] : 0.f;

  // quantize + LDS writes
  #pragma unroll
  for (int k = 0; k < 5; ++k){
    s16x8 qv;
    #pragma unroll
    for (int ci = 0; ci < 8; ++ci)
      qv[ci] = (short)f2bf(quant1(v[k][ci], rinv, s, hs));
    int u = (grp_r[k]*(LCP*2) + c*2 + grp_half[k]) ^ ((c >> 2) & 7);
    ldsv[u] = qv;
  }
  if (t_act){
    s16x8 qv;
    #pragma unroll
    for (int ci = 0; ci < 8; ++ci)
      qv[ci] = (short)f2bf(quant1(tv[ci], rinv, s, hs));
    int u = (t_r*(LCP*2) + t_c*2 + t_half) ^ ((t_c >> 2) & 7);
    ldsv[u] = qv;
  }
  __syncthreads();

  // ---- phase C: MFMA conv from LDS ----
  const int colg = lane & 15;
  const int g    = lane >> 4;
  const int hlf  = g & 1;        // ci half this lane reads
  const int tlg  = g >> 1;       // 0: even taps, 1: odd taps

  int kr[5], kw[5];
  #pragma unroll
  for (int m = 0; m < 5; ++m){
    int t = 2*m + tlg; if (t > 8) t = 8;   // tap 9: A=0, read tap 8 (finite)
    kr[m] = (t*11) >> 5;                   // t/3 for t in [0,8]
    kw[m] = t - kr[m]*3;
  }
  s16x8 A[5];
  const s16x8* pA = reinterpret_cast<const s16x8*>(packA);
  #pragma unroll
  for (int m = 0; m < 5; ++m) A[m] = pA[m*64 + lane];

  f32x4 acc[2][4] = {};
  #pragma unroll
  for (int q = 0; q < 2; ++q){
    const int r_out = wid*2 + q;
    #pragma unroll
    for (int n = 0; n < 4; ++n){
      #pragma unroll
      for (int m = 0; m < 5; ++m){
        int cc = n*16 + colg + kw[m];
        int u = ((r_out + kr[m])*(LCP*2) + cc*2 + hlf) ^ ((cc >> 2) & 7);
        s16x8 bv = ldsv[u];
        acc[q][n] = __builtin_amdgcn_mfma_f32_16x16x32_bf16(A[m], bv, acc[q][n], 0, 0, 0);
      }
    }
  }

  // ---- epilogue: dequant + bias; D layout col=lane&15 (pixel), row=g*4+j (cout)
  #pragma unroll
  for (int j = 0; j < 4; ++j){
    const int co = g*4 + j;
    const float sc = s * sw[co];
    const float bb = bias[co];
    #pragma unroll
    for (int q = 0; q < 2; ++q){
      const int h = h0 + wid*2 + q;
      float* op = out + ((size_t)(b*16 + co) << 16) + h*256 + w0 + colg;
      #pragma unroll
      for (int n = 0; n < 4; ++n)
        op[n*16] = acc[q][n][j] * sc + bb;
    }
  }
}

extern "C" void kernel_launch(void* const* d_in, const int* in_sizes, int n_in,
                              void* d_out, int out_size, void* d_ws, size_t ws_size,
                              hipStream_t stream){
  const float* x    = (const float*)d_in[0];
  const float* wq   = (const float*)d_in[1];
  const float* sw   = (const float*)d_in[2];
  const float* bias = (const float*)d_in[3];
  float* out = (float*)d_out;
  unsigned* wmax = (unsigned*)d_ws;
  unsigned short* packA = (unsigned short*)((char*)d_ws + 64);

  setup_kernel<<<1, 64, 0, stream>>>(wq, wmax, packA);
  absmax_kernel<<<2048, 256, 0, stream>>>(x, wmax, (B_*16*H_*W_)/4);
  fconv_kernel<<<B_*(H_/ROWS)*(W_/64), 256, 0, stream>>>(x, sw, bias, wmax, packA, out);
}

// Round 6
// 116.889 us; speedup vs baseline: 2.6052x; 1.0062x over previous
//
#include <hip/hip_runtime.h>
#include <hip/hip_bf16.h>

#define B_    32
#define H_    256
#define W_    256
#define ROWS  8            // output rows per block
#define LR    (ROWS + 2)   // 10 LDS rows (halo)
#define LCP   68           // padded cols -> row stride 136 16B-units (mult of 8 keeps XOR bijective)
// ws layout: [0,4)=wmax | [64,5184)=packA (5120 B)

typedef float f32x4 __attribute__((ext_vector_type(4)));
typedef short s16x8 __attribute__((ext_vector_type(8)));

__device__ inline unsigned short f2bf(float f){
  __hip_bfloat16 h = __float2bfloat16(f);
  return __builtin_bit_cast(unsigned short, h);
}

// exact round-half-even of x/s via reciprocal + exact fma residual correction
__device__ inline float quant1(float v, float rinv, float s, float hs){
  float q0 = rintf(v * rinv);
  float d  = fmaf(q0, -s, v);        // ~ s*(v/s - q0), one rounding
  q0 += (d >  hs) ? 1.f : 0.f;
  q0 -= (d < -hs) ? 1.f : 0.f;
  return fminf(fmaxf(q0, -127.f), 127.f);
}

// --- kernel 1: global max|x| (one atomic per block) + packA build in block 0 ---
// packA: 5 MFMAs of 16x16x32 cover K=144 (9 taps x 16 cin); 5th MFMA upper
// half (tap 9) is zero weights. A lane layout: co = lane&15,
// kappa = (lane>>4)*8+i; tap = 2m + (kappa>>4), ci = kappa&15. (verified r1,3,4,5)
__global__ __launch_bounds__(256) void absmax_kernel(const float* __restrict__ x,
                                                     const float* __restrict__ wq,
                                                     unsigned* __restrict__ wmax,
                                                     unsigned short* __restrict__ packA,
                                                     int n4){
  __shared__ float red[4];
  int idx = blockIdx.x*blockDim.x + threadIdx.x;
  int stride = gridDim.x*blockDim.x;
  float m = 0.f;
  for (int i = idx; i < n4; i += stride){
    float4 v = reinterpret_cast<const float4*>(x)[i];
    m = fmaxf(m, fmaxf(fmaxf(fabsf(v.x), fabsf(v.y)), fmaxf(fabsf(v.z), fabsf(v.w))));
  }
  #pragma unroll
  for (int off = 32; off > 0; off >>= 1)
    m = fmaxf(m, __shfl_xor(m, off));
  int lane = threadIdx.x & 63, wid = threadIdx.x >> 6;
  if (lane == 0) red[wid] = m;
  __syncthreads();
  if (threadIdx.x == 0){
    float mm = fmaxf(fmaxf(red[0], red[1]), fmaxf(red[2], red[3]));
    atomicMax(wmax, __float_as_uint(mm));
  }
  // pack weights (block 0, wave 0) -- visible to fconv via kernel boundary
  if (blockIdx.x == 0 && threadIdx.x < 64){
    int l = threadIdx.x;
    int co = l & 15;
    int g  = l >> 4;
    for (int mm2 = 0; mm2 < 5; ++mm2){
      for (int i = 0; i < 8; ++i){
        int kappa = g*8 + i;
        int tap = 2*mm2 + (kappa >> 4);
        int ci  = kappa & 15;
        float v = (tap <= 8) ? wq[(co*16 + ci)*9 + tap] : 0.f;
        packA[(mm2*64 + l)*8 + i] = f2bf(v);
      }
    }
  }
}

// --- kernel 2: fused quantize + int conv (exact in bf16 MFMA) + dequant ---
// block = (b, 8-row group, 64-px strip), 512 threads / 8 waves.
// Phase Q: 20 (row, ci-half) groups + 2-col tail into XOR-swizzled LDS.
// Phase C: each wave: 1 output row x 4 col-chunks x 5 MFMAs = 20 MFMAs.
__global__ __launch_bounds__(512) void fconv_kernel(const float* __restrict__ x,
                                                    const float* __restrict__ sw,
                                                    const float* __restrict__ bias,
                                                    const unsigned* __restrict__ wmax,
                                                    const unsigned short* __restrict__ packA,
                                                    float* __restrict__ out){
  const float s    = __uint_as_float(*wmax) * 0.0078125f;  // max|x| / 128
  const float rinv = 1.0f / s;
  const float hs   = 0.5f * s;
  const int bx    = blockIdx.x;
  const int strip = bx & 3;
  const int hg    = (bx >> 2) & 31;
  const int b     = bx >> 7;
  const int w0    = strip * 64;
  const int h0    = hg * ROWS;

  __shared__ __align__(16) unsigned short lds[LR*LCP*16];
  s16x8* ldsv = reinterpret_cast<s16x8*>(lds);

  const int tid  = threadIdx.x;
  const int lane = tid & 63;
  const int wid  = tid >> 6;     // 0..7

  // ---- phase Q ----
  const int c   = lane;
  const int win = w0 - 1 + c;
  const bool colok = (unsigned)win < 256u;

  int   grp_r[3], grp_half[3];
  const float* grp_p[3];
  bool  grp_ok[3], grp_act[3];
  #pragma unroll
  for (int k = 0; k < 3; ++k){
    int gi = wid + 8*k;
    grp_act[k] = gi < 20;
    int r = gi >> 1, half = gi & 1;
    int hin = h0 + r - 1;
    bool rowok = (unsigned)hin < 256u;
    grp_r[k] = r; grp_half[k] = half;
    grp_ok[k] = grp_act[k] && rowok && colok;
    grp_p[k] = x + ((size_t)(b*16 + half*8) << 16) + (size_t)(rowok ? hin : 0)*256 + win;
  }

  float v[3][8];
  #pragma unroll
  for (int k = 0; k < 3; ++k)
    #pragma unroll
    for (int ci = 0; ci < 8; ++ci)
      v[k][ci] = grp_ok[k] ? grp_p[k][(size_t)ci << 16] : 0.f;

  // tail: cols 64,65 for all (r, half) -> 40 slots on wave 7
  float tv[8];
  int t_r = 0, t_half = 0, t_c = 0;
  const bool t_act = (tid >= 448) && (tid < 488);
  if (t_act){
    int t = tid - 448;
    t_c    = 64 + (t & 1);
    t_half = (t >> 1) & 1;
    t_r    = t >> 2;
    int hin = h0 + t_r - 1;
    bool rowok = (unsigned)hin < 256u;
    int twin = w0 - 1 + t_c;
    bool ok = rowok && ((unsigned)twin < 256u);
    const float* xp = x + ((size_t)(b*16 + t_half*8) << 16) + (size_t)(rowok ? hin : 0)*256 + twin;
    #pragma unroll
    for (int ci = 0; ci < 8; ++ci)
      tv[ci] = ok ? xp[(size_t)ci << 16] : 0.f;
  }

  #pragma unroll
  for (int k = 0; k < 3; ++k){
    if (grp_act[k]){
      s16x8 qv;
      #pragma unroll
      for (int ci = 0; ci < 8; ++ci)
        qv[ci] = (short)f2bf(quant1(v[k][ci], rinv, s, hs));
      int u = (grp_r[k]*(LCP*2) + c*2 + grp_half[k]) ^ ((c >> 2) & 7);
      ldsv[u] = qv;
    }
  }
  if (t_act){
    s16x8 qv;
    #pragma unroll
    for (int ci = 0; ci < 8; ++ci)
      qv[ci] = (short)f2bf(quant1(tv[ci], rinv, s, hs));
    int u = (t_r*(LCP*2) + t_c*2 + t_half) ^ ((t_c >> 2) & 7);
    ldsv[u] = qv;
  }
  __syncthreads();

  // ---- phase C: one output row per wave ----
  const int colg = lane & 15;
  const int g    = lane >> 4;
  const int hlf  = g & 1;        // ci half this lane reads
  const int tlg  = g >> 1;       // 0: even taps, 1: odd taps

  int kr[5], kw[5];
  #pragma unroll
  for (int m = 0; m < 5; ++m){
    int t = 2*m + tlg; if (t > 8) t = 8;   // tap 9: A=0, read tap 8 (finite)
    kr[m] = (t*11) >> 5;                   // t/3 for t in [0,8]
    kw[m] = t - kr[m]*3;
  }
  s16x8 A[5];
  const s16x8* pA = reinterpret_cast<const s16x8*>(packA);
  #pragma unroll
  for (int m = 0; m < 5; ++m) A[m] = pA[m*64 + lane];

  f32x4 acc[4] = {};
  #pragma unroll
  for (int n = 0; n < 4; ++n){
    #pragma unroll
    for (int m = 0; m < 5; ++m){
      int cc = n*16 + colg + kw[m];
      int u = ((wid + kr[m])*(LCP*2) + cc*2 + hlf) ^ ((cc >> 2) & 7);
      s16x8 bv = ldsv[u];
      acc[n] = __builtin_amdgcn_mfma_f32_16x16x32_bf16(A[m], bv, acc[n], 0, 0, 0);
    }
  }

  // ---- epilogue: dequant + bias; D layout col=lane&15 (pixel), row=g*4+j (cout)
  const int h = h0 + wid;
  #pragma unroll
  for (int j = 0; j < 4; ++j){
    const int co = g*4 + j;
    const float sc = s * sw[co];
    const float bb = bias[co];
    float* op = out + ((size_t)(b*16 + co) << 16) + h*256 + w0 + colg;
    #pragma unroll
    for (int n = 0; n < 4; ++n)
      op[n*16] = acc[n][j] * sc + bb;
  }
}

extern "C" void kernel_launch(void* const* d_in, const int* in_sizes, int n_in,
                              void* d_out, int out_size, void* d_ws, size_t ws_size,
                              hipStream_t stream){
  const float* x    = (const float*)d_in[0];
  const float* wq   = (const float*)d_in[1];
  const float* sw   = (const float*)d_in[2];
  const float* bias = (const float*)d_in[3];
  float* out = (float*)d_out;
  unsigned* wmax = (unsigned*)d_ws;
  unsigned short* packA = (unsigned short*)((char*)d_ws + 64);

  hipMemsetAsync(wmax, 0, 4, stream);   // reset running max (graph-legal async)
  absmax_kernel<<<2048, 256, 0, stream>>>(x, wq, wmax, packA, (B_*16*H_*W_)/4);
  fconv_kernel<<<B_*(H_/ROWS)*(W_/64), 512, 0, stream>>>(x, sw, bias, wmax, packA, out);
}

// Round 7
// 107.867 us; speedup vs baseline: 2.8231x; 1.0836x over previous
//
#include <hip/hip_runtime.h>
#include <hip/hip_bf16.h>

#define B_    32
#define H_    256
#define W_    256
#define ROWS  8            // output rows per tile
#define LR    (ROWS + 2)   // 10 LDS rows (halo)
#define LCP   68           // padded cols -> row stride 136 16B-units (mult of 8 keeps XOR bijective)
#define BUFU  (LR*LCP*2)   // 1360 s16x8 units per LDS buffer
#define NT    4            // tiles per block
// ws layout: [0,4)=wmax | [64,5184)=packA (5120 B)

typedef float f32x4 __attribute__((ext_vector_type(4)));
typedef short s16x8 __attribute__((ext_vector_type(8)));

__device__ inline unsigned short f2bf(float f){
  __hip_bfloat16 h = __float2bfloat16(f);
  return __builtin_bit_cast(unsigned short, h);
}

// exact round-half-even of x/s via reciprocal + exact fma residual correction
__device__ inline float quant1(float v, float rinv, float s, float hs){
  float q0 = rintf(v * rinv);
  float d  = fmaf(q0, -s, v);        // ~ s*(v/s - q0), one rounding
  q0 += (d >  hs) ? 1.f : 0.f;
  q0 -= (d < -hs) ? 1.f : 0.f;
  return fminf(fmaxf(q0, -127.f), 127.f);
}

// tile id t: hg fastest (consecutive tiles share halo rows), then strip, then b
__device__ __forceinline__ void tile_decode(int t, int& b, int& w0, int& h0){
  int hg = t & 31; int r = t >> 5;
  w0 = (r & 3) * 64; b = r >> 2; h0 = hg * ROWS;
}

// --- kernel 1: global max|x| (one atomic per block) + packA build in block 0 ---
// packA: 5 MFMAs of 16x16x32 cover K=144 (9 taps x 16 cin); 5th MFMA upper
// half (tap 9) is zero weights. A lane layout: co = lane&15,
// kappa = (lane>>4)*8+i; tap = 2m + (kappa>>4), ci = kappa&15. (verified r1,3-6)
__global__ __launch_bounds__(256) void absmax_kernel(const float* __restrict__ x,
                                                     const float* __restrict__ wq,
                                                     unsigned* __restrict__ wmax,
                                                     unsigned short* __restrict__ packA,
                                                     int n4){
  __shared__ float red[4];
  int idx = blockIdx.x*blockDim.x + threadIdx.x;
  int stride = gridDim.x*blockDim.x;
  float m = 0.f;
  for (int i = idx; i < n4; i += stride){
    float4 v = reinterpret_cast<const float4*>(x)[i];
    m = fmaxf(m, fmaxf(fmaxf(fabsf(v.x), fabsf(v.y)), fmaxf(fabsf(v.z), fabsf(v.w))));
  }
  #pragma unroll
  for (int off = 32; off > 0; off >>= 1)
    m = fmaxf(m, __shfl_xor(m, off));
  int lane = threadIdx.x & 63, wid = threadIdx.x >> 6;
  if (lane == 0) red[wid] = m;
  __syncthreads();
  if (threadIdx.x == 0){
    float mm = fmaxf(fmaxf(red[0], red[1]), fmaxf(red[2], red[3]));
    atomicMax(wmax, __float_as_uint(mm));
  }
  if (blockIdx.x == 0 && threadIdx.x < 64){
    int l = threadIdx.x;
    int co = l & 15;
    int g  = l >> 4;
    for (int mm2 = 0; mm2 < 5; ++mm2){
      for (int i = 0; i < 8; ++i){
        int kappa = g*8 + i;
        int tap = 2*mm2 + (kappa >> 4);
        int ci  = kappa & 15;
        float v = (tap <= 8) ? wq[(co*16 + ci)*9 + tap] : 0.f;
        packA[(mm2*64 + l)*8 + i] = f2bf(v);
      }
    }
  }
}

// ---- Q phase helpers (indexing verified r4-r6) ----
__device__ __forceinline__ void q_load(const float* __restrict__ x,
                                       int b, int w0, int h0,
                                       int tid, int lane, int wid,
                                       float v[3][8], float tv[8]){
  const int c = lane;
  const int win = w0 - 1 + c;
  const bool colok = (unsigned)win < 256u;
  #pragma unroll
  for (int k = 0; k < 3; ++k){
    int gi = wid + 8*k;
    bool act = gi < 20;
    int r = gi >> 1, half = gi & 1;
    int hin = h0 + r - 1;
    bool rowok = (unsigned)hin < 256u;
    bool ok = act && rowok && colok;
    const float* p = x + ((size_t)(b*16 + half*8) << 16) + (size_t)(rowok ? hin : 0)*256 + win;
    #pragma unroll
    for (int ci = 0; ci < 8; ++ci)
      v[k][ci] = ok ? p[(size_t)ci << 16] : 0.f;
  }
  if (tid >= 448 && tid < 488){
    int t = tid - 448;
    int t_c = 64 + (t & 1), t_half = (t >> 1) & 1, t_r = t >> 2;
    int hin = h0 + t_r - 1;
    bool rowok = (unsigned)hin < 256u;
    int twin = w0 - 1 + t_c;
    bool ok = rowok && ((unsigned)twin < 256u);
    const float* p = x + ((size_t)(b*16 + t_half*8) << 16) + (size_t)(rowok ? hin : 0)*256 + twin;
    #pragma unroll
    for (int ci = 0; ci < 8; ++ci)
      tv[ci] = ok ? p[(size_t)ci << 16] : 0.f;
  }
}

__device__ __forceinline__ void q_write(s16x8* ldsv, int bufoff,
                                        int tid, int lane, int wid,
                                        const float v[3][8], const float tv[8],
                                        float rinv, float s, float hs){
  const int c = lane;
  #pragma unroll
  for (int k = 0; k < 3; ++k){
    int gi = wid + 8*k;
    if (gi < 20){
      int r = gi >> 1, half = gi & 1;
      s16x8 qv;
      #pragma unroll
      for (int ci = 0; ci < 8; ++ci)
        qv[ci] = (short)f2bf(quant1(v[k][ci], rinv, s, hs));
      int u = (r*(LCP*2) + c*2 + half) ^ ((c >> 2) & 7);
      ldsv[bufoff + u] = qv;
    }
  }
  if (tid >= 448 && tid < 488){
    int t = tid - 448;
    int t_c = 64 + (t & 1), t_half = (t >> 1) & 1, t_r = t >> 2;
    s16x8 qv;
    #pragma unroll
    for (int ci = 0; ci < 8; ++ci)
      qv[ci] = (short)f2bf(quant1(tv[ci], rinv, s, hs));
    int u = (t_r*(LCP*2) + t_c*2 + t_half) ^ ((t_c >> 2) & 7);
    ldsv[bufoff + u] = qv;
  }
}

// ---- C phase: one output row per wave, 4 col-chunks x 5 MFMAs ----
__device__ __forceinline__ void c_phase(const s16x8* ldsv, int bufoff,
                                        const s16x8 A[5], const int kr[5], const int kw[5],
                                        int lane, int wid, int b, int w0, int h0,
                                        const float sc[4], const float bb[4],
                                        float* __restrict__ out){
  const int colg = lane & 15;
  const int g    = lane >> 4;
  const int hlf  = g & 1;
  f32x4 acc[4] = {};
  #pragma unroll
  for (int n = 0; n < 4; ++n){
    #pragma unroll
    for (int m = 0; m < 5; ++m){
      int cc = n*16 + colg + kw[m];
      int u = ((wid + kr[m])*(LCP*2) + cc*2 + hlf) ^ ((cc >> 2) & 7);
      acc[n] = __builtin_amdgcn_mfma_f32_16x16x32_bf16(A[m], ldsv[bufoff + u], acc[n], 0, 0, 0);
    }
  }
  const int h = h0 + wid;
  #pragma unroll
  for (int j = 0; j < 4; ++j){
    const int co = g*4 + j;
    float* op = out + ((size_t)(b*16 + co) << 16) + h*256 + w0 + colg;
    #pragma unroll
    for (int n = 0; n < 4; ++n)
      op[n*16] = acc[n][j] * sc[j] + bb[j];
  }
}

// --- kernel 2: persistent fused quant+conv, double-buffered across 4 tiles ---
__global__ __launch_bounds__(512) void fconv_kernel(const float* __restrict__ x,
                                                    const float* __restrict__ sw,
                                                    const float* __restrict__ bias,
                                                    const unsigned* __restrict__ wmax,
                                                    const unsigned short* __restrict__ packA,
                                                    float* __restrict__ out){
  const float s    = __uint_as_float(*wmax) * 0.0078125f;  // max|x| / 128
  const float rinv = 1.0f / s;
  const float hs   = 0.5f * s;

  __shared__ __align__(16) unsigned short lds[2*LR*LCP*16];
  s16x8* ldsv = reinterpret_cast<s16x8*>(lds);

  const int tid  = threadIdx.x;
  const int lane = tid & 63;
  const int wid  = tid >> 6;     // 0..7

  // loop-invariant: A fragments, tap geometry, dequant constants
  const int g   = lane >> 4;
  const int tlg = g >> 1;
  int kr[5], kw[5];
  #pragma unroll
  for (int m = 0; m < 5; ++m){
    int t = 2*m + tlg; if (t > 8) t = 8;   // tap 9: A=0, read tap 8 (finite)
    kr[m] = (t*11) >> 5;                   // t/3 for t in [0,8]
    kw[m] = t - kr[m]*3;
  }
  s16x8 A[5];
  const s16x8* pA = reinterpret_cast<const s16x8*>(packA);
  #pragma unroll
  for (int m = 0; m < 5; ++m) A[m] = pA[m*64 + lane];
  float sc[4], bb[4];
  #pragma unroll
  for (int j = 0; j < 4; ++j){
    sc[j] = s * sw[g*4 + j];
    bb[j] = bias[g*4 + j];
  }

  // XCD-chunked tile assignment: 8 chunks x 512 tiles; 128 blocks/chunk x NT
  const int bid = blockIdx.x;
  const int t0  = (bid & 7)*512 + (bid >> 3)*NT;

  int b, w0, h0;
  float v[3][8], tv[8];

  // prologue: tile t0 into buffer 0
  tile_decode(t0, b, w0, h0);
  q_load(x, b, w0, h0, tid, lane, wid, v, tv);
  q_write(ldsv, 0, tid, lane, wid, v, tv, rinv, s, hs);
  __syncthreads();

  #pragma unroll
  for (int k = 0; k < NT; ++k){
    const int cur = k & 1;
    if (k < NT-1){
      int b2, w2, h2; tile_decode(t0 + k + 1, b2, w2, h2);
      q_load(x, b2, w2, h2, tid, lane, wid, v, tv);   // issue early (T14)
    }
    tile_decode(t0 + k, b, w0, h0);
    c_phase(ldsv, cur*BUFU, A, kr, kw, lane, wid, b, w0, h0, sc, bb, out);
    if (k < NT-1)
      q_write(ldsv, (cur^1)*BUFU, tid, lane, wid, v, tv, rinv, s, hs);
    __syncthreads();
  }
}

extern "C" void kernel_launch(void* const* d_in, const int* in_sizes, int n_in,
                              void* d_out, int out_size, void* d_ws, size_t ws_size,
                              hipStream_t stream){
  const float* x    = (const float*)d_in[0];
  const float* wq   = (const float*)d_in[1];
  const float* sw   = (const float*)d_in[2];
  const float* bias = (const float*)d_in[3];
  float* out = (float*)d_out;
  unsigned* wmax = (unsigned*)d_ws;
  unsigned short* packA = (unsigned short*)((char*)d_ws + 64);

  hipMemsetAsync(wmax, 0, 4, stream);   // reset running max (graph-legal async)
  absmax_kernel<<<2048, 256, 0, stream>>>(x, wq, wmax, packA, (B_*16*H_*W_)/4);
  fconv_kernel<<<(B_*(H_/ROWS)*(W_/64))/NT, 512, 0, stream>>>(x, sw, bias, wmax, packA, out);
}

// Round 8
// 85.861 us; speedup vs baseline: 3.5466x; 1.2563x over previous
//
#include <hip/hip_runtime.h>
#include <hip/hip_bf16.h>

#define B_    32
#define H_    256
#define W_    256
#define ROWS  8            // output rows per tile
#define LR    (ROWS + 2)   // 10 LDS rows (halo)
#define LCP   68           // padded cols -> row stride 136 16B-units (mult of 8 keeps XOR bijective)
#define RSTR  (LCP*2)      // 136 units per row
#define BUFU  (LR*RSTR)    // 1360 s16x8 units per LDS buffer
#define NT    4            // tiles per block (vertically adjacent)
// ws layout: [64,5184)=packA | [8192,16384)=pmax[2048] floats

typedef float f32x4 __attribute__((ext_vector_type(4)));
typedef short s16x8 __attribute__((ext_vector_type(8)));

__device__ inline unsigned short f2bf(float f){
  __hip_bfloat16 h = __float2bfloat16(f);
  return __builtin_bit_cast(unsigned short, h);
}

// exact round-half-even of x/s via reciprocal + exact fma residual correction
__device__ inline float quant1(float v, float rinv, float s, float hs){
  float q0 = rintf(v * rinv);
  float d  = fmaf(q0, -s, v);        // ~ s*(v/s - q0), one rounding
  q0 += (d >  hs) ? 1.f : 0.f;
  q0 -= (d < -hs) ? 1.f : 0.f;
  return fminf(fmaxf(q0, -127.f), 127.f);
}

// tile id t: hg fastest (consecutive tiles vertically adjacent), then strip, b
__device__ __forceinline__ void tile_decode(int t, int& b, int& w0, int& h0){
  int hg = t & 31; int r = t >> 5;
  w0 = (r & 3) * 64; b = r >> 2; h0 = hg * ROWS;
}

// --- kernel 1: per-block max|x| -> pmax[bid] (no atomic, no reset needed)
//     + packA build in block 0 (layout verified r1,3-7) ---
__global__ __launch_bounds__(256) void absmax_kernel(const float* __restrict__ x,
                                                     const float* __restrict__ wq,
                                                     float* __restrict__ pmax,
                                                     unsigned short* __restrict__ packA,
                                                     int n4){
  __shared__ float red[4];
  int idx = blockIdx.x*blockDim.x + threadIdx.x;
  int stride = gridDim.x*blockDim.x;
  float m = 0.f;
  for (int i = idx; i < n4; i += stride){
    float4 v = reinterpret_cast<const float4*>(x)[i];
    m = fmaxf(m, fmaxf(fmaxf(fabsf(v.x), fabsf(v.y)), fmaxf(fabsf(v.z), fabsf(v.w))));
  }
  #pragma unroll
  for (int off = 32; off > 0; off >>= 1)
    m = fmaxf(m, __shfl_xor(m, off));
  int lane = threadIdx.x & 63, wid = threadIdx.x >> 6;
  if (lane == 0) red[wid] = m;
  __syncthreads();
  if (threadIdx.x == 0)
    pmax[blockIdx.x] = fmaxf(fmaxf(red[0], red[1]), fmaxf(red[2], red[3]));
  if (blockIdx.x == 0 && threadIdx.x < 64){
    int l = threadIdx.x;
    int co = l & 15;
    int g  = l >> 4;
    for (int mm2 = 0; mm2 < 5; ++mm2){
      for (int i = 0; i < 8; ++i){
        int kappa = g*8 + i;
        int tap = 2*mm2 + (kappa >> 4);
        int ci  = kappa & 15;
        float v = (tap <= 8) ? wq[(co*16 + ci)*9 + tap] : 0.f;
        packA[(mm2*64 + l)*8 + i] = f2bf(v);
      }
    }
  }
}

// ---- Q helpers: NGRP (row,half) groups starting at LDS row RBASE ----
// full tile: NGRP=20, RBASE=0; partial (halo rows reused): NGRP=16, RBASE=2.
template<int NGRP, int RBASE>
__device__ __forceinline__ void q_load_t(const float* __restrict__ x,
                                         int b, int w0, int h0,
                                         int tid, int lane, int wid,
                                         float v[][8], float tv[8]){
  const int KMAX  = (NGRP + 7) / 8;
  const int NTAIL = (NGRP / 2) * 4;
  const int c = lane;
  const int win = w0 - 1 + c;
  const bool colok = (unsigned)win < 256u;
  #pragma unroll
  for (int k = 0; k < KMAX; ++k){
    int gi = wid + 8*k;
    bool act = gi < NGRP;
    int r = RBASE + (gi >> 1), half = gi & 1;
    int hin = h0 + r - 1;
    bool rowok = (unsigned)hin < 256u;
    bool ok = act && rowok && colok;
    const float* p = x + ((size_t)(b*16 + half*8) << 16) + (size_t)(rowok ? hin : 0)*256 + win;
    #pragma unroll
    for (int ci = 0; ci < 8; ++ci)
      v[k][ci] = ok ? p[(size_t)ci << 16] : 0.f;
  }
  if (tid >= 448 && tid < 448 + NTAIL){
    int t = tid - 448;
    int t_c = 64 + (t & 1), t_half = (t >> 1) & 1, t_r = RBASE + (t >> 2);
    int hin = h0 + t_r - 1;
    bool rowok = (unsigned)hin < 256u;
    int twin = w0 - 1 + t_c;
    bool ok = rowok && ((unsigned)twin < 256u);
    const float* p = x + ((size_t)(b*16 + t_half*8) << 16) + (size_t)(rowok ? hin : 0)*256 + twin;
    #pragma unroll
    for (int ci = 0; ci < 8; ++ci)
      tv[ci] = ok ? p[(size_t)ci << 16] : 0.f;
  }
}

template<int NGRP, int RBASE>
__device__ __forceinline__ void q_write_t(s16x8* ldsv, int bufoff,
                                          int tid, int lane, int wid,
                                          const float v[][8], const float tv[8],
                                          float rinv, float s, float hs){
  const int KMAX  = (NGRP + 7) / 8;
  const int NTAIL = (NGRP / 2) * 4;
  const int c = lane;
  #pragma unroll
  for (int k = 0; k < KMAX; ++k){
    int gi = wid + 8*k;
    if (gi < NGRP){
      int r = RBASE + (gi >> 1), half = gi & 1;
      s16x8 qv;
      #pragma unroll
      for (int ci = 0; ci < 8; ++ci)
        qv[ci] = (short)f2bf(quant1(v[k][ci], rinv, s, hs));
      int u = (r*RSTR + c*2 + half) ^ ((c >> 2) & 7);
      ldsv[bufoff + u] = qv;
    }
  }
  if (tid >= 448 && tid < 448 + NTAIL){
    int t = tid - 448;
    int t_c = 64 + (t & 1), t_half = (t >> 1) & 1, t_r = RBASE + (t >> 2);
    s16x8 qv;
    #pragma unroll
    for (int ci = 0; ci < 8; ++ci)
      qv[ci] = (short)f2bf(quant1(tv[ci], rinv, s, hs));
    int u = (t_r*RSTR + t_c*2 + t_half) ^ ((t_c >> 2) & 7);
    ldsv[bufoff + u] = qv;
  }
}

// ---- C phase: one output row per wave, 4 col-chunks x 5 MFMAs (verified r6,7)
__device__ __forceinline__ void c_phase(const s16x8* ldsv, int bufoff,
                                        const s16x8 A[5], const int kr[5], const int kw[5],
                                        int lane, int wid, int b, int w0, int h0,
                                        const float sc[4], const float bb[4],
                                        float* __restrict__ out){
  const int colg = lane & 15;
  const int g    = lane >> 4;
  const int hlf  = g & 1;
  f32x4 acc[4] = {};
  #pragma unroll
  for (int n = 0; n < 4; ++n){
    #pragma unroll
    for (int m = 0; m < 5; ++m){
      int cc = n*16 + colg + kw[m];
      int u = ((wid + kr[m])*RSTR + cc*2 + hlf) ^ ((cc >> 2) & 7);
      acc[n] = __builtin_amdgcn_mfma_f32_16x16x32_bf16(A[m], ldsv[bufoff + u], acc[n], 0, 0, 0);
    }
  }
  const int h = h0 + wid;
  #pragma unroll
  for (int j = 0; j < 4; ++j){
    const int co = g*4 + j;
    float* op = out + ((size_t)(b*16 + co) << 16) + h*256 + w0 + colg;
    #pragma unroll
    for (int n = 0; n < 4; ++n)
      op[n*16] = acc[n][j] * sc[j] + bb[j];
  }
}

// --- kernel 2: persistent fused quant+conv, double-buffered, halo-row reuse ---
__global__ __launch_bounds__(512) void fconv_kernel(const float* __restrict__ x,
                                                    const float* __restrict__ sw,
                                                    const float* __restrict__ bias,
                                                    const float* __restrict__ pmax,
                                                    const unsigned short* __restrict__ packA,
                                                    float* __restrict__ out){
  __shared__ __align__(16) unsigned short lds[2*LR*LCP*16];
  __shared__ float redmax[8];
  s16x8* ldsv = reinterpret_cast<s16x8*>(lds);

  const int tid  = threadIdx.x;
  const int lane = tid & 63;
  const int wid  = tid >> 6;     // 0..7

  // XCD-chunked: 8 chunks x 512 tiles; within chunk, NT vertically-adjacent tiles
  const int bid = blockIdx.x;
  const int t0  = (bid & 7)*512 + (bid >> 3)*NT;

  int b, w0, h0;
  float v[3][8], tv[8];

  // prologue tile t0: issue global loads FIRST (pmax reduce hides under them)
  tile_decode(t0, b, w0, h0);
  q_load_t<20,0>(x, b, w0, h0, tid, lane, wid, v, tv);

  // global-max reduce over 2048 partials (8KB, L2-resident)
  float4 pv = reinterpret_cast<const float4*>(pmax)[tid];
  float m = fmaxf(fmaxf(pv.x, pv.y), fmaxf(pv.z, pv.w));
  #pragma unroll
  for (int off = 32; off > 0; off >>= 1)
    m = fmaxf(m, __shfl_xor(m, off));
  if (lane == 0) redmax[wid] = m;
  __syncthreads();
  float gm = redmax[0];
  #pragma unroll
  for (int i = 1; i < 8; ++i) gm = fmaxf(gm, redmax[i]);

  const float s    = gm * 0.0078125f;   // max|x| / 128
  const float rinv = 1.0f / s;
  const float hs   = 0.5f * s;

  // loop-invariant A fragments, tap geometry, dequant constants
  const int g   = lane >> 4;
  const int tlg = g >> 1;
  int kr[5], kw[5];
  #pragma unroll
  for (int mm = 0; mm < 5; ++mm){
    int t = 2*mm + tlg; if (t > 8) t = 8;  // tap 9: A=0, read tap 8 (finite)
    kr[mm] = (t*11) >> 5;
    kw[mm] = t - kr[mm]*3;
  }
  s16x8 A[5];
  const s16x8* pA = reinterpret_cast<const s16x8*>(packA);
  #pragma unroll
  for (int mm = 0; mm < 5; ++mm) A[mm] = pA[mm*64 + lane];
  float sc[4], bb[4];
  #pragma unroll
  for (int j = 0; j < 4; ++j){
    sc[j] = s * sw[g*4 + j];
    bb[j] = bias[g*4 + j];
  }

  q_write_t<20,0>(ldsv, 0, tid, lane, wid, v, tv, rinv, s, hs);
  __syncthreads();

  #pragma unroll
  for (int k = 0; k < NT; ++k){
    const int cur = k & 1;
    if (k < NT-1){
      int b2, w2, h2; tile_decode(t0 + k + 1, b2, w2, h2);
      q_load_t<16,2>(x, b2, w2, h2, tid, lane, wid, v, tv);  // rows 2..9 only
      // halo-row reuse: tile k rows 8,9 == tile k+1 rows 0,1 (swizzle row-local)
      if (tid < 2*RSTR){
        int rr = tid >= RSTR;
        int cc = tid - rr*RSTR;
        ldsv[(cur^1)*BUFU + rr*RSTR + cc] = ldsv[cur*BUFU + (8+rr)*RSTR + cc];
      }
    }
    tile_decode(t0 + k, b, w0, h0);
    c_phase(ldsv, cur*BUFU, A, kr, kw, lane, wid, b, w0, h0, sc, bb, out);
    if (k < NT-1)
      q_write_t<16,2>(ldsv, (cur^1)*BUFU, tid, lane, wid, v, tv, rinv, s, hs);
    __syncthreads();
  }
}

extern "C" void kernel_launch(void* const* d_in, const int* in_sizes, int n_in,
                              void* d_out, int out_size, void* d_ws, size_t ws_size,
                              hipStream_t stream){
  const float* x    = (const float*)d_in[0];
  const float* wq   = (const float*)d_in[1];
  const float* sw   = (const float*)d_in[2];
  const float* bias = (const float*)d_in[3];
  float* out = (float*)d_out;
  unsigned short* packA = (unsigned short*)((char*)d_ws + 64);
  float* pmax = (float*)((char*)d_ws + 8192);

  absmax_kernel<<<2048, 256, 0, stream>>>(x, wq, pmax, packA, (B_*16*H_*W_)/4);
  fconv_kernel<<<(B_*(H_/ROWS)*(W_/64))/NT, 512, 0, stream>>>(x, sw, bias, pmax, packA, out);
}